// Round 2
// baseline (582.505 us; speedup 1.0000x reference)
//
#include <hip/hip_runtime.h>

#define IN_F 128
#define HID 256
#define HID2 128

// ---------------- CSR build ----------------
__global__ void count_deg(const int* __restrict__ col, int* __restrict__ deg, int E) {
    int e = blockIdx.x * blockDim.x + threadIdx.x;
    if (e < E) atomicAdd(&deg[col[e]], 1);
}

__global__ __launch_bounds__(1024) void scan_deg(const int* __restrict__ deg,
                                                 int* __restrict__ rp, int n) {
    __shared__ int wsums[16];
    int t = threadIdx.x, lane = t & 63, wid = t >> 6;
    int carry = 0;
    for (int base = 0; base < n; base += 1024) {
        int i = base + t;
        int v = (i < n) ? deg[i] : 0;
        int x = v;
#pragma unroll
        for (int d = 1; d < 64; d <<= 1) {
            int y = __shfl_up(x, d, 64);
            if (lane >= d) x += y;
        }
        if (lane == 63) wsums[wid] = x;
        __syncthreads();
        if (t < 16) {
            int s = wsums[t];
#pragma unroll
            for (int d = 1; d < 16; d <<= 1) {
                int y = __shfl_up(s, d, 64);
                if (t >= d) s += y;
            }
            wsums[t] = s;
        }
        __syncthreads();
        int woff = wid ? wsums[wid - 1] : 0;
        if (i < n) rp[i] = carry + woff + x - v;
        carry += wsums[15];
        __syncthreads();
    }
    if (t == 0) rp[n] = carry;
}

__global__ void fill_csr(const int* __restrict__ row, const int* __restrict__ col,
                         const int* __restrict__ rp, int* __restrict__ fill,
                         int* __restrict__ csr, int E) {
    int e = blockIdx.x * blockDim.x + threadIdx.x;
    if (e < E) {
        int c = col[e];
        int p = atomicAdd(&fill[c], 1);
        csr[rp[c] + p] = row[e];
    }
}

// ---------------- Layer 1 aggregation: out[n,:] = deg_inv[n] * sum x[src,:] ----------------
__global__ __launch_bounds__(128) void agg_gather(const float* __restrict__ x,
                                                  const int* __restrict__ rp,
                                                  const int* __restrict__ csr,
                                                  const int* __restrict__ deg,
                                                  float* __restrict__ out) {
    int n = blockIdx.x, t = threadIdx.x;
    int s = rp[n], e = rp[n + 1];
    float a0 = 0.f, a1 = 0.f;
    int i = s;
    for (; i + 1 < e; i += 2) {
        int s0 = csr[i], s1 = csr[i + 1];
        a0 += x[(size_t)s0 * IN_F + t];
        a1 += x[(size_t)s1 * IN_F + t];
    }
    if (i < e) a0 += x[(size_t)csr[i] * IN_F + t];
    float dinv = 1.f / fmaxf((float)deg[n], 1.f);
    out[(size_t)n * IN_F + t] = (a0 + a1) * dinv;
}

// ---------------- Tiled GEMM: C[M,N] = A[M,K] @ W[N,K]^T (+bias, relu) ----------------
// BM=BN=64, KC=64 chunks, 256 threads, 4x4 micro-tile per thread.
// Thread t: rows m0 + 4*(t>>4) + i, cols n0 + (t&15) + 16*j.
// Both A and W are k-major, so LDS tiles need no transpose; float4 reads along k.
// Row stride 68 floats: 16B-aligned, a-reads & w-reads 2-way bank alias (free).
template<bool RELU_BIAS>
__global__ __launch_bounds__(256) void gemm_t4(const float* __restrict__ A,
                                               const float* __restrict__ W,
                                               const float* __restrict__ bias,
                                               float* __restrict__ C,
                                               int M, int N, int K) {
    __shared__ float As[64][68];
    __shared__ float Ws[64][68];
    int m0 = blockIdx.x * 64, n0 = blockIdx.y * 64;
    int t = threadIdx.x;
    int tr = t >> 4, tc = t & 15;
    int vrows = M - m0; if (vrows > 64) vrows = 64;
    float acc[4][4] = {{0.f}};

    for (int kc = 0; kc < K; kc += 64) {
#pragma unroll
        for (int it = 0; it < 4; it++) {
            int idx = t + 256 * it;
            int r = idx >> 4, c4 = (idx & 15) * 4;
            float4 v = make_float4(0.f, 0.f, 0.f, 0.f);
            if (r < vrows) v = *(const float4*)&A[(size_t)(m0 + r) * K + kc + c4];
            *(float4*)&As[r][c4] = v;
            *(float4*)&Ws[r][c4] = *(const float4*)&W[(size_t)(n0 + r) * K + kc + c4];
        }
        __syncthreads();
#pragma unroll
        for (int k4 = 0; k4 < 16; k4++) {
            float4 a[4], w[4];
#pragma unroll
            for (int i = 0; i < 4; i++) a[i] = *(const float4*)&As[4 * tr + i][4 * k4];
#pragma unroll
            for (int j = 0; j < 4; j++) w[j] = *(const float4*)&Ws[tc + 16 * j][4 * k4];
#pragma unroll
            for (int i = 0; i < 4; i++)
#pragma unroll
                for (int j = 0; j < 4; j++)
                    acc[i][j] += a[i].x * w[j].x + a[i].y * w[j].y +
                                 a[i].z * w[j].z + a[i].w * w[j].w;
        }
        __syncthreads();
    }

#pragma unroll
    for (int i = 0; i < 4; i++) {
        int m = m0 + 4 * tr + i;
        if (m < M) {
#pragma unroll
            for (int j = 0; j < 4; j++) {
                int n = n0 + tc + 16 * j;
                float v = acc[i][j];
                if (RELU_BIAS) v = fmaxf(v + bias[n], 0.f);
                C[(size_t)m * N + n] = v;
            }
        }
    }
}

// ------- Layer 2 aggregation fused with bias+relu and final [128]->[2] GEMM -------
__global__ __launch_bounds__(128) void agg2_out(const float* __restrict__ z,
                                                const int* __restrict__ rp,
                                                const int* __restrict__ csr,
                                                const int* __restrict__ deg,
                                                const float* __restrict__ b2,
                                                const float* __restrict__ W3,
                                                const float* __restrict__ b3,
                                                float* __restrict__ out) {
    int n = blockIdx.x, t = threadIdx.x;
    int s = rp[n], e = rp[n + 1];
    float a0 = 0.f, a1 = 0.f;
    int i = s;
    for (; i + 1 < e; i += 2) {
        int s0 = csr[i], s1 = csr[i + 1];
        a0 += z[(size_t)s0 * HID2 + t];
        a1 += z[(size_t)s1 * HID2 + t];
    }
    if (i < e) a0 += z[(size_t)csr[i] * HID2 + t];
    float dinv = 1.f / fmaxf((float)deg[n], 1.f);
    float h = fmaxf((a0 + a1) * dinv + b2[t], 0.f);
    float p0 = h * W3[t];
    float p1 = h * W3[HID2 + t];
    __shared__ float red[4];
#pragma unroll
    for (int d = 32; d > 0; d >>= 1) {
        p0 += __shfl_down(p0, d, 64);
        p1 += __shfl_down(p1, d, 64);
    }
    int wid = t >> 6;
    if ((t & 63) == 0) { red[wid * 2] = p0; red[wid * 2 + 1] = p1; }
    __syncthreads();
    if (t == 0) {
        out[(size_t)n * 2]     = red[0] + red[2] + b3[0];
        out[(size_t)n * 2 + 1] = red[1] + red[3] + b3[1];
    }
}

extern "C" void kernel_launch(void* const* d_in, const int* in_sizes, int n_in,
                              void* d_out, int out_size, void* d_ws, size_t ws_size,
                              hipStream_t stream) {
    const float* x  = (const float*)d_in[0];
    const int*   ei = (const int*)d_in[1];
    const float* W1 = (const float*)d_in[3];
    const float* b1 = (const float*)d_in[4];
    const float* W2 = (const float*)d_in[5];
    const float* b2 = (const float*)d_in[6];
    const float* W3 = (const float*)d_in[7];
    const float* b3 = (const float*)d_in[8];
    float* out = (float*)d_out;

    int N = in_sizes[0] / IN_F;   // 50000
    int E = in_sizes[1] / 2;      // 800000
    const int* row = ei;
    const int* col = ei + E;

    char* base = (char*)d_ws;
    size_t off = 0;
    auto alloc = [&](size_t bytes) -> void* {
        off = (off + 255) & ~(size_t)255;
        void* p = base + off;
        off += bytes;
        return p;
    };
    int*   deg  = (int*)alloc((size_t)2 * N * 4);   // deg + fill contiguous for one memset
    int*   fill = deg + N;
    int*   rp   = (int*)alloc((size_t)(N + 1) * 4);
    int*   csr  = (int*)alloc((size_t)E * 4);
    float* h1   = (float*)alloc((size_t)N * HID * 4);
    float* f2   = (float*)alloc((size_t)N * IN_F * 4);  // agg1, later reused for z2

    hipMemsetAsync(deg, 0, (size_t)2 * N * 4, stream);
    int eb = (E + 255) / 256;
    count_deg<<<eb, 256, 0, stream>>>(col, deg, E);
    scan_deg<<<1, 1024, 0, stream>>>(deg, rp, N);
    fill_csr<<<eb, 256, 0, stream>>>(row, col, rp, fill, csr, E);

    agg_gather<<<N, 128, 0, stream>>>(x, rp, csr, deg, f2);

    int mt = (N + 63) / 64;  // 782
    gemm_t4<true><<<dim3(mt, HID / 64), 256, 0, stream>>>(f2, W1, b1, h1, N, HID, IN_F);
    gemm_t4<false><<<dim3(mt, HID2 / 64), 256, 0, stream>>>(h1, W2, nullptr, f2, N, HID2, HID);
    agg2_out<<<N, 128, 0, stream>>>(f2, rp, csr, deg, b2, W3, b3, out);
}

// Round 3
// 402.727 us; speedup vs baseline: 1.4464x; 1.4464x over previous
//
#include <hip/hip_runtime.h>

#define IN_F 128
#define HID 256
#define HID2 128

#define BM 128
#define BN 64
#define BK 32

// ---------------- CSR build ----------------
__global__ void count_deg(const int* __restrict__ col, int* __restrict__ deg, int E) {
    int e = blockIdx.x * blockDim.x + threadIdx.x;
    if (e < E) atomicAdd(&deg[col[e]], 1);
}

// 3-phase parallel exclusive scan: block-local inclusive -> scan block sums -> add offsets
__global__ __launch_bounds__(256) void scan_block(const int* __restrict__ deg,
                                                  int* __restrict__ tmp,
                                                  int* __restrict__ bsum, int n) {
    int b = blockIdx.x, t = threadIdx.x, i = b * 256 + t;
    int lane = t & 63, w = t >> 6;
    int v = (i < n) ? deg[i] : 0;
    int x = v;
#pragma unroll
    for (int d = 1; d < 64; d <<= 1) {
        int y = __shfl_up(x, d, 64);
        if (lane >= d) x += y;
    }
    __shared__ int ws[4];
    if (lane == 63) ws[w] = x;
    __syncthreads();
    if (t < 4) {
        int s = ws[t];
#pragma unroll
        for (int d = 1; d < 4; d <<= 1) {
            int y = __shfl_up(s, d, 64);
            if (t >= d) s += y;
        }
        ws[t] = s;
    }
    __syncthreads();
    x += (w ? ws[w - 1] : 0);
    if (i < n) tmp[i] = x;      // inclusive within block
    if (t == 255) bsum[b] = x;
}

__global__ __launch_bounds__(256) void scan_bsums(int* __restrict__ bsum, int nb) {
    int t = threadIdx.x, lane = t & 63, w = t >> 6;
    int v = (t < nb) ? bsum[t] : 0;
    int x = v;
#pragma unroll
    for (int d = 1; d < 64; d <<= 1) {
        int y = __shfl_up(x, d, 64);
        if (lane >= d) x += y;
    }
    __shared__ int ws[4];
    if (lane == 63) ws[w] = x;
    __syncthreads();
    if (t < 4) {
        int s = ws[t];
#pragma unroll
        for (int d = 1; d < 4; d <<= 1) {
            int y = __shfl_up(s, d, 64);
            if (t >= d) s += y;
        }
        ws[t] = s;
    }
    __syncthreads();
    x += (w ? ws[w - 1] : 0);
    if (t < nb) bsum[t] = x;    // inclusive
}

__global__ void scan_add(const int* __restrict__ tmp, const int* __restrict__ bsum,
                         int* __restrict__ rp, int n) {
    int b = blockIdx.x, i = b * 256 + threadIdx.x;
    if (i < n) {
        rp[i + 1] = tmp[i] + (b ? bsum[b - 1] : 0);
        if (i == 0) rp[0] = 0;
    }
}

__global__ void fill_csr(const int* __restrict__ row, const int* __restrict__ col,
                         const int* __restrict__ rp, int* __restrict__ fill,
                         int* __restrict__ csr, int E) {
    int e = blockIdx.x * blockDim.x + threadIdx.x;
    if (e < E) {
        int c = col[e];
        int p = atomicAdd(&fill[c], 1);
        csr[rp[c] + p] = row[e];
    }
}

// ------- Layer 1 aggregation: wave-per-node, float2/lane (row = 64 lanes x 8B) -------
__global__ __launch_bounds__(256) void agg_gather(const float* __restrict__ x,
                                                  const int* __restrict__ rp,
                                                  const int* __restrict__ csr,
                                                  float* __restrict__ out, int N) {
    int w = threadIdx.x >> 6, lane = threadIdx.x & 63;
    int n = blockIdx.x * 4 + w;
    if (n >= N) return;
    int s = rp[n], e = rp[n + 1];
    const float2* x2 = (const float2*)x;
    float ax0 = 0.f, ay0 = 0.f, ax1 = 0.f, ay1 = 0.f;
    int i = s;
    for (; i + 1 < e; i += 2) {
        int s0 = csr[i], s1 = csr[i + 1];
        float2 v0 = x2[(size_t)s0 * 64 + lane];
        float2 v1 = x2[(size_t)s1 * 64 + lane];
        ax0 += v0.x; ay0 += v0.y; ax1 += v1.x; ay1 += v1.y;
    }
    if (i < e) {
        float2 v = x2[(size_t)csr[i] * 64 + lane];
        ax0 += v.x; ay0 += v.y;
    }
    float dinv = 1.f / fmaxf((float)(e - s), 1.f);
    float2* o2 = (float2*)out;
    o2[(size_t)n * 64 + lane] = make_float2((ax0 + ax1) * dinv, (ay0 + ay1) * dinv);
}

// ---------------- GEMM: C[M,N] = A[M,K] @ W[N,K]^T (+bias,relu) ----------------
// 128x64 block tile, BK=32, 256 threads, 8x4 micro-tile.
// LDS tiles stored k-major TRANSPOSED: As[k][m], Ws[k][n] -> inner-loop reads are
// conflict-free (a: 4 uniq addrs x 4 banks = 16 banks; w: 16 uniq float4 spanning
// all 32 banks 2-way = free) and one b128 w-read yields all 4 n-values.
// Register prefetch of next chunk overlaps compute.
template<bool RELU_BIAS>
__global__ __launch_bounds__(256) void gemm_t8(const float* __restrict__ A,
                                               const float* __restrict__ W,
                                               const float* __restrict__ bias,
                                               float* __restrict__ C,
                                               int M, int N, int K) {
    __shared__ float As[BK][BM + 4];   // stride 132 floats (528B, 16B-aligned)
    __shared__ float Ws[BK][BN + 4];   // stride 68 floats (272B, 16B-aligned)
    int m0 = blockIdx.x * BM, n0 = blockIdx.y * BN;
    int t = threadIdx.x;
    int tr = t >> 4, tc = t & 15;      // rows m0+8tr+i, cols n0+4tc+j

    // staging assignment
    int am[4], ak4[4];
#pragma unroll
    for (int it = 0; it < 4; it++) { int id = t + 256 * it; am[it] = id >> 3; ak4[it] = id & 7; }
    int wn[2], wk4[2];
#pragma unroll
    for (int it = 0; it < 2; it++) { int id = t + 256 * it; wn[it] = id >> 3; wk4[it] = id & 7; }

    float4 av[4], wv[2];
    auto load_chunk = [&](int kc) {
#pragma unroll
        for (int it = 0; it < 4; it++) {
            int m = m0 + am[it];
            av[it] = (m < M) ? *(const float4*)&A[(size_t)m * K + kc + 4 * ak4[it]]
                             : make_float4(0.f, 0.f, 0.f, 0.f);
        }
#pragma unroll
        for (int it = 0; it < 2; it++)
            wv[it] = *(const float4*)&W[(size_t)(n0 + wn[it]) * K + kc + 4 * wk4[it]];
    };

    load_chunk(0);
    float acc[8][4];
#pragma unroll
    for (int i = 0; i < 8; i++)
#pragma unroll
        for (int j = 0; j < 4; j++) acc[i][j] = 0.f;

    for (int kc = 0; kc < K; kc += BK) {
        __syncthreads();
#pragma unroll
        for (int it = 0; it < 4; it++) {
            As[4 * ak4[it] + 0][am[it]] = av[it].x;
            As[4 * ak4[it] + 1][am[it]] = av[it].y;
            As[4 * ak4[it] + 2][am[it]] = av[it].z;
            As[4 * ak4[it] + 3][am[it]] = av[it].w;
        }
#pragma unroll
        for (int it = 0; it < 2; it++) {
            Ws[4 * wk4[it] + 0][wn[it]] = wv[it].x;
            Ws[4 * wk4[it] + 1][wn[it]] = wv[it].y;
            Ws[4 * wk4[it] + 2][wn[it]] = wv[it].z;
            Ws[4 * wk4[it] + 3][wn[it]] = wv[it].w;
        }
        __syncthreads();
        if (kc + BK < K) load_chunk(kc + BK);   // prefetch next chunk into regs
#pragma unroll
        for (int k = 0; k < BK; k++) {
            float4 w = *(const float4*)&Ws[k][4 * tc];
            float4 a0 = *(const float4*)&As[k][8 * tr];
            float4 a1 = *(const float4*)&As[k][8 * tr + 4];
            float a[8] = {a0.x, a0.y, a0.z, a0.w, a1.x, a1.y, a1.z, a1.w};
#pragma unroll
            for (int i = 0; i < 8; i++) {
                acc[i][0] += a[i] * w.x;
                acc[i][1] += a[i] * w.y;
                acc[i][2] += a[i] * w.z;
                acc[i][3] += a[i] * w.w;
            }
        }
    }

    float4 b4 = make_float4(0.f, 0.f, 0.f, 0.f);
    if (RELU_BIAS) b4 = *(const float4*)&bias[n0 + 4 * tc];
#pragma unroll
    for (int i = 0; i < 8; i++) {
        int m = m0 + 8 * tr + i;
        if (m < M) {
            float4 v = make_float4(acc[i][0], acc[i][1], acc[i][2], acc[i][3]);
            if (RELU_BIAS) {
                v.x = fmaxf(v.x + b4.x, 0.f);
                v.y = fmaxf(v.y + b4.y, 0.f);
                v.z = fmaxf(v.z + b4.z, 0.f);
                v.w = fmaxf(v.w + b4.w, 0.f);
            }
            *(float4*)&C[(size_t)m * N + n0 + 4 * tc] = v;
        }
    }
}

// ------- Layer 2 agg (wave-per-node) fused with bias+relu and final [128]->[2] GEMM -------
__global__ __launch_bounds__(256) void agg2_out(const float* __restrict__ z,
                                                const int* __restrict__ rp,
                                                const int* __restrict__ csr,
                                                const float* __restrict__ b2,
                                                const float* __restrict__ W3,
                                                const float* __restrict__ b3,
                                                float* __restrict__ out, int N) {
    int w = threadIdx.x >> 6, lane = threadIdx.x & 63;
    int n = blockIdx.x * 4 + w;
    if (n >= N) return;
    int s = rp[n], e = rp[n + 1];
    const float2* z2 = (const float2*)z;
    float ax0 = 0.f, ay0 = 0.f, ax1 = 0.f, ay1 = 0.f;
    int i = s;
    for (; i + 1 < e; i += 2) {
        int s0 = csr[i], s1 = csr[i + 1];
        float2 v0 = z2[(size_t)s0 * 64 + lane];
        float2 v1 = z2[(size_t)s1 * 64 + lane];
        ax0 += v0.x; ay0 += v0.y; ax1 += v1.x; ay1 += v1.y;
    }
    if (i < e) {
        float2 v = z2[(size_t)csr[i] * 64 + lane];
        ax0 += v.x; ay0 += v.y;
    }
    float dinv = 1.f / fmaxf((float)(e - s), 1.f);
    float hx = fmaxf((ax0 + ax1) * dinv + b2[2 * lane], 0.f);
    float hy = fmaxf((ay0 + ay1) * dinv + b2[2 * lane + 1], 0.f);
    float p0 = hx * W3[2 * lane] + hy * W3[2 * lane + 1];
    float p1 = hx * W3[HID2 + 2 * lane] + hy * W3[HID2 + 2 * lane + 1];
#pragma unroll
    for (int d = 32; d > 0; d >>= 1) {
        p0 += __shfl_down(p0, d, 64);
        p1 += __shfl_down(p1, d, 64);
    }
    if (lane == 0) {
        out[(size_t)n * 2]     = p0 + b3[0];
        out[(size_t)n * 2 + 1] = p1 + b3[1];
    }
}

extern "C" void kernel_launch(void* const* d_in, const int* in_sizes, int n_in,
                              void* d_out, int out_size, void* d_ws, size_t ws_size,
                              hipStream_t stream) {
    const float* x  = (const float*)d_in[0];
    const int*   ei = (const int*)d_in[1];
    const float* W1 = (const float*)d_in[3];
    const float* b1 = (const float*)d_in[4];
    const float* W2 = (const float*)d_in[5];
    const float* b2 = (const float*)d_in[6];
    const float* W3 = (const float*)d_in[7];
    const float* b3 = (const float*)d_in[8];
    float* out = (float*)d_out;

    int N = in_sizes[0] / IN_F;   // 50000
    int E = in_sizes[1] / 2;      // 800000
    const int* row = ei;
    const int* col = ei + E;

    char* base = (char*)d_ws;
    size_t off = 0;
    auto alloc = [&](size_t bytes) -> void* {
        off = (off + 255) & ~(size_t)255;
        void* p = base + off;
        off += bytes;
        return p;
    };
    int*   deg  = (int*)alloc((size_t)2 * N * 4);   // deg + fill, one memset
    int*   fill = deg + N;
    int*   rp   = (int*)alloc((size_t)(N + 1) * 4);
    int*   tmp  = (int*)alloc((size_t)N * 4);
    int*   bsum = (int*)alloc(1024);
    int*   csr  = (int*)alloc((size_t)E * 4);
    float* h1   = (float*)alloc((size_t)N * HID * 4);
    float* f2   = (float*)alloc((size_t)N * IN_F * 4);  // agg1, later reused as z2

    hipMemsetAsync(deg, 0, (size_t)2 * N * 4, stream);
    int eb = (E + 255) / 256;
    int nb = (N + 255) / 256;   // 196
    count_deg<<<eb, 256, 0, stream>>>(col, deg, E);
    scan_block<<<nb, 256, 0, stream>>>(deg, tmp, bsum, N);
    scan_bsums<<<1, 256, 0, stream>>>(bsum, nb);
    scan_add<<<nb, 256, 0, stream>>>(tmp, bsum, rp, N);
    fill_csr<<<eb, 256, 0, stream>>>(row, col, rp, fill, csr, E);

    agg_gather<<<(N + 3) / 4, 256, 0, stream>>>(x, rp, csr, f2, N);

    int mt = (N + BM - 1) / BM;  // 391
    gemm_t8<true><<<dim3(mt, HID / BN), 256, 0, stream>>>(f2, W1, b1, h1, N, HID, IN_F);
    gemm_t8<false><<<dim3(mt, HID2 / BN), 256, 0, stream>>>(h1, W2, nullptr, f2, N, HID2, HID);
    agg2_out<<<(N + 3) / 4, 256, 0, stream>>>(f2, rp, csr, b2, W3, b3, out, N);
}